// Round 5
// baseline (159.532 us; speedup 1.0000x reference)
//
#include <hip/hip_runtime.h>
#include <math.h>

#define HW 2304           // 48*48
#define O192 192
#define SCALE_F 0.35355339059327373f   // 8^-0.5

typedef unsigned int u32;
typedef __attribute__((address_space(1))) const u32 gu32;
typedef __attribute__((address_space(3))) u32 lu32;
// async global->LDS DMA, 16B per lane; LDS dest = wave-uniform base + lane*16
__device__ __forceinline__ void dma16(const void* g, void* l) {
  __builtin_amdgcn_global_load_lds((gu32*)g, (lu32*)l, 16, 0, 0);
}

// ---------------- Kernel A: 1x1 conv -> q,k (QKV) and v (V2) ----------------
__global__ __launch_bounds__(256) void qkv_kernel(
    const float* __restrict__ F, const float* __restrict__ W,
    float* __restrict__ QKV, float* __restrict__ V2) {
  __shared__ __align__(16) float sW[384];   // two o0 sets x {q,k,v} rows x 64
  int blk = blockIdx.x;
  int idx0 = blk * 256;
  int r0 = idx0 / HW;
  int r1 = (idx0 + 255) / HW;
  int tid = threadIdx.x;
  if (tid < 192) {
    int g = tid >> 6, c = tid & 63;
    sW[tid]       = W[((r0 & 63) + g * 64) * 64 + c];
    sW[192 + tid] = W[((r1 & 63) + g * 64) * 64 + c];
  }
  __syncthreads();
  int idx = idx0 + tid;
  int p  = idx % HW;
  int r  = idx / HW;
  int o0 = r & 63;
  int b  = r >> 6;
  const float4* w4 = (const float4*)(sW + ((r == r0) ? 0 : 192));
  const float* f = F + (b * 64) * HW + p;
  float aq = 0.f, ak = 0.f, av = 0.f;
  #pragma unroll 4
  for (int c4 = 0; c4 < 16; c4++) {
    float4 wq = w4[c4];
    float4 wk = w4[16 + c4];
    float4 wv = w4[32 + c4];
    float f0 = f[(c4 * 4 + 0) * HW];
    float f1 = f[(c4 * 4 + 1) * HW];
    float f2 = f[(c4 * 4 + 2) * HW];
    float f3 = f[(c4 * 4 + 3) * HW];
    aq = fmaf(wq.x, f0, aq); ak = fmaf(wk.x, f0, ak); av = fmaf(wv.x, f0, av);
    aq = fmaf(wq.y, f1, aq); ak = fmaf(wk.y, f1, ak); av = fmaf(wv.y, f1, av);
    aq = fmaf(wq.z, f2, aq); ak = fmaf(wk.z, f2, ak); av = fmaf(wv.z, f2, av);
    aq = fmaf(wq.w, f3, aq); ak = fmaf(wk.w, f3, ak); av = fmaf(wv.w, f3, av);
  }
  float* qp = QKV + (b * HW + p) * O192;
  qp[o0]      = aq;
  qp[o0 + 64] = ak;
  V2[(((b << 3) + (o0 >> 3)) * HW + p) * 8 + (o0 & 7)] = av;
}

// ---------------- Kernel B: 11x11 stride-8 conv + bias + exact GELU ----------
__global__ __launch_bounds__(256) void conv_kernel(
    const float* __restrict__ QKV, const float* __restrict__ Wq,
    const float* __restrict__ Bq, const float* __restrict__ Wk,
    const float* __restrict__ Bk, float* __restrict__ QD) {
  __shared__ float sW[7744];
  __shared__ float sRed[4 * 64 * 6];
  int blk = blockIdx.x;
  int xcd = blk & 7;
  int T = xcd >> 2, b = (xcd >> 1) & 1, s = xcd & 1;
  int idx = (blk >> 3) * 2 + s;
  int o  = idx / 6;
  int oy = idx % 6;
  const float* Wg = T ? Wk : Wq;
  for (int i = threadIdx.x; i < 7744; i += 256) sW[i] = Wg[o * 7744 + i];
  __syncthreads();
  int wv = threadIdx.x >> 6;
  int c  = threadIdx.x & 63;
  const float* base = QKV + b * (HW * O192) + T * 64 + c;
  float acc[6];
  #pragma unroll
  for (int ox = 0; ox < 6; ox++) acc[ox] = 0.f;
  for (int kyi = 0; kyi < 3; kyi++) {
    int ky = wv * 3 + kyi;
    if (ky > 10) break;
    int y = oy * 8 - 2 + ky;
    if ((unsigned)y < 48u) {
      float xrow[48];
      #pragma unroll
      for (int x = 0; x < 48; x++) xrow[x] = base[(y * 48 + x) * O192];
      #pragma unroll
      for (int kx = 0; kx < 11; kx++) {
        float wt = sW[c * 121 + ky * 11 + kx];
        #pragma unroll
        for (int ox = 0; ox < 6; ox++) {
          int x = ox * 8 - 2 + kx;
          if (x >= 0 && x < 48) acc[ox] = fmaf(xrow[x], wt, acc[ox]);
        }
      }
    }
  }
  #pragma unroll
  for (int ox = 0; ox < 6; ox++) sRed[(wv * 64 + c) * 6 + ox] = acc[ox];
  __syncthreads();
  if (threadIdx.x < 64) {
    int t = threadIdx.x;
    float r[6];
    #pragma unroll
    for (int ox = 0; ox < 6; ox++)
      r[ox] = sRed[t * 6 + ox] + sRed[(64 + t) * 6 + ox]
            + sRed[(128 + t) * 6 + ox] + sRed[(192 + t) * 6 + ox];
    #pragma unroll
    for (int off = 32; off; off >>= 1) {
      #pragma unroll
      for (int ox = 0; ox < 6; ox++) r[ox] += __shfl_down(r[ox], off, 64);
    }
    if (t == 0) {
      float bias = T ? Bk[o] : Bq[o];
      #pragma unroll
      for (int ox = 0; ox < 6; ox++) {
        float g = r[ox] + bias;
        float ge = 0.5f * g * (1.0f + erff(g * 0.70710678118654752f));
        QD[((T * 2 + b) * 64 + o) * 36 + oy * 6 + ox] = ge;
      }
    }
  }
}

// ---------------- Kernel D: factored attention, c-split, 8 rows/lane --------
// 576 blocks = (bh:16, S:9 supertile of 256 rows, q:4 jy-quarter of 12).
// 8 waves; wave w owns jx in [6w,6w+6).  Lane: l32 = lane&31 row-slot,
// chalf = lane>>5 selects V channels 0-3 / 4-7.  Each lane covers 8 rows
// (r = 32*k8 + l32) x 4 channels -> ONE b128 V read per (jy,i) per wave.
// E tile computed in prologue from QD (dots_kernel fused).  Z computed by
// both chalf groups -> x0.5 at write.  Partials to Pnum/PZ; combine sums.
#define OFF_V   0        // 4608 f : V quarter [12jy][48jx][8c]
#define OFF_EA  4608     // 3072 f : eA [jyL][l32*8+k8]
#define OFF_PHT 7680     // 384  f : PH^T [jy][c]
#define OFF_PWT 8064     // 384  f : PW^T [jx][c]
#define OFF_E4  8448     // 144  f : E [J][k4]
#define OFF_U   8592     // 2560 f : union: sQ (2048) then sRed (2560)
#define SBUF_N  11152    // 44.6 KB

__global__ __launch_bounds__(512, 4) void attn_kernel(
    const float* __restrict__ QKV, const float* __restrict__ V2,
    const float* __restrict__ QD, const float* __restrict__ PH,
    const float* __restrict__ PW, float* __restrict__ Pnum,
    float* __restrict__ PZ) {
  __shared__ __align__(16) float sB[SBUF_N];
  int blk = blockIdx.x;
  int bh = blk / 36;
  int rem = blk - bh * 36;
  int q = rem & 3, S = rem >> 2;
  int b = bh >> 3, h = bh & 7;
  int tid = threadIdx.x;
  int w = tid >> 6, lane = tid & 63;
  int l32 = lane & 31, chalf = lane >> 5;
  // ---- stage small tables ----
  if (tid < 384) {
    sB[OFF_PHT + tid] = PH[(tid & 7) * 48 + (tid >> 3)];
    sB[OFF_PWT + tid] = PW[(tid & 7) * 48 + (tid >> 3)];
  }
  if (tid < 144) {   // fused dots: E[J][k4] = exp(scale * qd_I . kd_J)
    int J = tid >> 2, k4 = tid & 3;
    const float* qd = QD + ((0 + b) * 64 + h * 8) * 36 + (S * 4 + k4);
    const float* kd = QD + ((2 + b) * 64 + h * 8) * 36 + J;
    float acc = 0.f;
    #pragma unroll
    for (int c8 = 0; c8 < 8; c8++) acc = fmaf(qd[c8 * 36], kd[c8 * 36], acc);
    sB[OFF_E4 + J * 4 + k4] = __expf(SCALE_F * acc);
  }
  { // q rows of this supertile: sQ[row][8]
    int row = tid >> 1, half = tid & 1;
    *(float4*)(sB + OFF_U + tid * 4) =
      *(const float4*)(QKV + (b * HW + S * 256 + row) * O192 + h * 8 + half * 4);
  }
  { // V quarter via DMA: 18 chunks x 1 KiB, contiguous
    const char* src = (const char*)(V2 + (size_t)bh * (HW * 8) + q * 4608);
    for (int m = w; m < 18; m += 8)
      dma16(src + m * 1024 + lane * 16, (char*)(sB + OFF_V) + m * 1024);
  }
  __syncthreads();
  // ---- eA table: exp(q_row . PH[:,jy]), layout [jyL][l32*8+k8] ----
  #pragma unroll
  for (int m = 0; m < 6; m++) {
    int flat = tid + m * 512;           // jyL*256 + row
    int jyL = flat >> 8, row = flat & 255;
    const float* qp = sB + OFF_U + row * 8;
    const float* pp = sB + OFF_PHT + (q * 12 + jyL) * 8;
    float d = qp[0]*pp[0]+qp[1]*pp[1]+qp[2]*pp[2]+qp[3]*pp[3]
            + qp[4]*pp[4]+qp[5]*pp[5]+qp[6]*pp[6]+qp[7]*pp[7];
    sB[OFF_EA + jyL * 256 + (row & 31) * 8 + (row >> 5)] = __expf(d);
  }
  // ---- eB regs: 8 rows x this wave's 6 jx ----
  float pw[6][8];
  #pragma unroll
  for (int i = 0; i < 6; i++) {
    float4 a = *(const float4*)(sB + OFF_PWT + (w * 6 + i) * 8);
    float4 c = *(const float4*)(sB + OFF_PWT + (w * 6 + i) * 8 + 4);
    pw[i][0]=a.x; pw[i][1]=a.y; pw[i][2]=a.z; pw[i][3]=a.w;
    pw[i][4]=c.x; pw[i][5]=c.y; pw[i][6]=c.z; pw[i][7]=c.w;
  }
  float eB[8][6];
  #pragma unroll
  for (int k8 = 0; k8 < 8; k8++) {
    const float* qp = sB + OFF_U + (k8 * 32 + l32) * 8;
    float4 qa = *(const float4*)qp;
    float4 qb = *(const float4*)(qp + 4);
    #pragma unroll
    for (int i = 0; i < 6; i++) {
      float d = qa.x*pw[i][0]+qa.y*pw[i][1]+qa.z*pw[i][2]+qa.w*pw[i][3]
              + qb.x*pw[i][4]+qb.y*pw[i][5]+qb.z*pw[i][6]+qb.w*pw[i][7];
      eB[k8][i] = __expf(d);
    }
  }
  float accv[8][4], zz[8];
  #pragma unroll
  for (int k8 = 0; k8 < 8; k8++) {
    zz[k8] = 0.f;
    #pragma unroll
    for (int c = 0; c < 4; c++) accv[k8][c] = 0.f;
  }
  __syncthreads();
  // ---- main loop over this quarter's 12 jy ----
  const float4* sV4 = (const float4*)(sB + OFF_V);
  for (int jyL = 0; jyL < 12; jyL++) {
    float4 ea0 = *(const float4*)(sB + OFF_EA + jyL * 256 + l32 * 8);
    float4 ea1 = *(const float4*)(sB + OFF_EA + jyL * 256 + l32 * 8 + 4);
    int cb = (q * 12 + jyL) * 48 + w * 6;     // global j at i=0 (wave-uniform)
    int J0 = cb >> 6, J1 = (cb + 5) >> 6;
    int ib = 64 - (cb & 63);                  // i >= ib uses J1 (wave-uniform)
    float4 e0 = *(const float4*)(sB + OFF_E4 + J0 * 4);
    float4 e1 = *(const float4*)(sB + OFF_E4 + J1 * 4);
    float a0[8], a1[8];
    a0[0]=ea0.x*e0.x; a0[1]=ea0.y*e0.x; a0[2]=ea0.z*e0.y; a0[3]=ea0.w*e0.y;
    a0[4]=ea1.x*e0.z; a0[5]=ea1.y*e0.z; a0[6]=ea1.z*e0.w; a0[7]=ea1.w*e0.w;
    a1[0]=ea0.x*e1.x; a1[1]=ea0.y*e1.x; a1[2]=ea0.z*e1.y; a1[3]=ea0.w*e1.y;
    a1[4]=ea1.x*e1.z; a1[5]=ea1.y*e1.z; a1[6]=ea1.z*e1.w; a1[7]=ea1.w*e1.w;
    #pragma unroll
    for (int i = 0; i < 6; i++) {
      float4 v = sV4[(jyL * 48 + w * 6 + i) * 2 + chalf];
      bool s0 = (i < ib);                     // wave-uniform select
      #pragma unroll
      for (int k8 = 0; k8 < 8; k8++) {
        float wgt = (s0 ? a0[k8] : a1[k8]) * eB[k8][i];
        accv[k8][0] = fmaf(wgt, v.x, accv[k8][0]);
        accv[k8][1] = fmaf(wgt, v.y, accv[k8][1]);
        accv[k8][2] = fmaf(wgt, v.z, accv[k8][2]);
        accv[k8][3] = fmaf(wgt, v.w, accv[k8][3]);
        zz[k8] += wgt;
      }
    }
  }
  // ---- cross-wave reduction: one 32-row group per round ----
  float* sU = sB + OFF_U;   // sQ dead
  #pragma unroll
  for (int k8 = 0; k8 < 8; k8++) {
    __syncthreads();
    {
      float* rp = sU + (w * 64 + lane) * 5;
      rp[0] = accv[k8][0]; rp[1] = accv[k8][1];
      rp[2] = accv[k8][2]; rp[3] = accv[k8][3];
      rp[4] = zz[k8];
    }
    __syncthreads();
    if (tid < 256) {
      int row32 = tid & 31, c = tid >> 5;     // c 0..7
      int ln = row32 + (c >> 2) * 32;
      float num = 0.f;
      #pragma unroll
      for (int ww = 0; ww < 8; ww++) num += sU[(ww * 64 + ln) * 5 + (c & 3)];
      Pnum[((q * 16 + bh) * 8 + c) * HW + S * 256 + k8 * 32 + row32] = num;
    } else if (tid < 288) {
      int row32 = tid & 31;
      float z = 0.f;
      #pragma unroll
      for (int ww = 0; ww < 8; ww++)
        z += sU[(ww * 64 + row32) * 5 + 4] + sU[(ww * 64 + 32 + row32) * 5 + 4];
      PZ[(q * 16 + bh) * HW + S * 256 + k8 * 32 + row32] = z * 0.5f;
    }
  }
}

// ---------------- Kernel E: combine 4 jy-quarters + normalize ---------------
__global__ __launch_bounds__(256) void combine_kernel(
    const float* __restrict__ Pnum, const float* __restrict__ PZ,
    float* __restrict__ out) {
  int t = blockIdx.x * 256 + threadIdx.x;   // 294912
  int row = t % HW;
  int rc = t / HW;        // bh*8 + c
  int c = rc & 7, bh = rc >> 3;
  float num = 0.f, z = 0.f;
  #pragma unroll
  for (int q = 0; q < 4; q++) {
    num += Pnum[((q * 16 + bh) * 8 + c) * HW + row];
    z   += PZ[(q * 16 + bh) * HW + row];
  }
  int b = bh >> 3, h = bh & 7;
  out[(b * 64 + h * 8 + c) * HW + row] = num / z;
}

extern "C" void kernel_launch(void* const* d_in, const int* in_sizes, int n_in,
                              void* d_out, int out_size, void* d_ws, size_t ws_size,
                              hipStream_t stream) {
  const float* F    = (const float*)d_in[0];
  const float* Wqkv = (const float*)d_in[1];
  const float* Wq   = (const float*)d_in[2];
  const float* Bq   = (const float*)d_in[3];
  const float* Wk   = (const float*)d_in[4];
  const float* Bk   = (const float*)d_in[5];
  const float* PH   = (const float*)d_in[6];
  const float* PW   = (const float*)d_in[7];
  float* out = (float*)d_out;

  float* ws   = (float*)d_ws;
  float* QKV  = ws;                        // 884736
  float* V2   = QKV + 2 * HW * O192;       // 294912
  float* QD   = V2 + 2 * 8 * HW * 8;       // 9216
  float* Pnum = QD + 2 * 2 * 64 * 36;      // 1179648
  float* PZ   = Pnum + 4 * 16 * 8 * HW;    // 147456

  qkv_kernel    <<<1152, 256, 0, stream>>>(F, Wqkv, QKV, V2);
  conv_kernel   <<<1536, 256, 0, stream>>>(QKV, Wq, Bq, Wk, Bk, QD);
  attn_kernel   <<<576,  512, 0, stream>>>(QKV, V2, QD, PH, PW, Pnum, PZ);
  combine_kernel<<<1152, 256, 0, stream>>>(Pnum, PZ, out);
}